// Round 10
// baseline (149.971 us; speedup 1.0000x reference)
//
#include <hip/hip_runtime.h>

#define BS 32
#define NA 512
#define ID 128
#define NH 8
#define HD 64
#define NHD 512   // NH*HD
#define NEG 0.2f
#define NC 32     // scalar chunk count (G=16) for zps/znp
#define CH 16
#define NW 8      // waves per k2 block (512 threads)
#define BPAD 136  // B LDS col stride (bf16 elems): 272B -> 2-way bank alias (free)

typedef short bf16x8 __attribute__((ext_vector_type(8)));
typedef float f32x4 __attribute__((ext_vector_type(4)));

__device__ inline unsigned f2bf_bits(float x) {   // RNE f32 -> bf16 bits
  unsigned u = __float_as_uint(x);
  return (u + 0x7FFFu + ((u >> 16) & 1u)) >> 16;
}

// split 8 floats into bf16 hi + bf16 lo fragments (static indices only)
__device__ inline void split8(const float4& x, const float4& y,
                              bf16x8& hi, bf16x8& lo) {
  float f[8] = {x.x, x.y, x.z, x.w, y.x, y.y, y.z, y.w};
  #pragma unroll
  for (int j = 0; j < 8; ++j) {
    unsigned hb = f2bf_bits(f[j]);
    float r = f[j] - __uint_as_float(hb << 16);
    unsigned lb = f2bf_bits(r);
    hi[j] = (short)hb;
    lo[j] = (short)lb;
  }
}

// K1 (MFMA): hp = h @ W via split-bf16 3-pass, fp32 accumulate (R4-verified)
// + s/t epilogue from resident accumulators (R7-verified 16-lane shfl tree).
// hp -> io (d_out); s,t -> d_ws.
__global__ __launch_bounds__(256, 4) void k1_mfma(
    const float* __restrict__ h, const float* __restrict__ W,
    const float* __restrict__ att, float* __restrict__ io,
    float* __restrict__ sG, float* __restrict__ tG) {
  __shared__ unsigned short Bhi[64 * BPAD];
  __shared__ unsigned short Blo[64 * BPAD];

  int blk = blockIdx.x;
  int mt = blk >> 3;            // M-tile 0..127 (128 rows each)
  int n0 = (blk & 7) * 64;      // N-tile start col
  int m0 = mt * 128;
  int b = mt >> 2;              // batch
  int nbase = (mt & 3) * 128;   // agent-row base within batch
  int head = n0 >> 6;
  int t = threadIdx.x;
  int lane = t & 63, w = t >> 6;
  int q = lane >> 4, ml = lane & 15;

  // ---- stage W[n0..n0+63] split+transposed into LDS ----
  {
    int c = t & 63, kq = t >> 6;
    const float* wsrc = W + (size_t)kq * 32 * NHD + n0 + c;
    #pragma unroll 4
    for (int kk = 0; kk < 32; ++kk) {
      int k = kq * 32 + kk;
      float x = wsrc[(size_t)kk * NHD];
      unsigned hb = f2bf_bits(x);
      float r = x - __uint_as_float(hb << 16);
      Bhi[c * BPAD + k] = (unsigned short)hb;
      Blo[c * BPAD + k] = (unsigned short)f2bf_bits(r);
    }
  }
  __syncthreads();

  f32x4 acc[2][4];
  #pragma unroll
  for (int mf = 0; mf < 2; ++mf)
    #pragma unroll
    for (int nf = 0; nf < 4; ++nf)
      acc[mf][nf] = (f32x4){0.f, 0.f, 0.f, 0.f};

  const float* A0 = h + (size_t)(m0 + w * 32 + ml) * ID;

  #pragma unroll
  for (int ks = 0; ks < 4; ++ks) {
    int ko = ks * 32 + q * 8;          // my k mapping: k = 8*quarter + elem
    bf16x8 ah[2], al[2];
    #pragma unroll
    for (int mf = 0; mf < 2; ++mf) {
      const float* ap = A0 + mf * 16 * ID + ko;
      float4 f0 = *(const float4*)ap;
      float4 f1 = *(const float4*)(ap + 4);
      split8(f0, f1, ah[mf], al[mf]);
    }
    #pragma unroll
    for (int nf = 0; nf < 4; ++nf) {
      int bo = (nf * 16 + ml) * BPAD + ko;   // same k mapping on B side
      bf16x8 bh = *(const bf16x8*)&Bhi[bo];
      bf16x8 bl = *(const bf16x8*)&Blo[bo];
      #pragma unroll
      for (int mf = 0; mf < 2; ++mf) {
        acc[mf][nf] = __builtin_amdgcn_mfma_f32_16x16x32_bf16(ah[mf], bh, acc[mf][nf], 0, 0, 0);
        acc[mf][nf] = __builtin_amdgcn_mfma_f32_16x16x32_bf16(ah[mf], bl, acc[mf][nf], 0, 0, 0);
        acc[mf][nf] = __builtin_amdgcn_mfma_f32_16x16x32_bf16(al[mf], bh, acc[mf][nf], 0, 0, 0);
      }
    }
  }

  // ---- hp store: D layout col=lane&15, row=4*(lane>>4)+reg (HW-verified) ----
  {
    float* ob = io + (((size_t)b * NH + head) * NA + nbase + w * 32) * HD + ml;
    #pragma unroll
    for (int mf = 0; mf < 2; ++mf)
      #pragma unroll
      for (int nf = 0; nf < 4; ++nf)
        #pragma unroll
        for (int r = 0; r < 4; ++r)
          ob[(size_t)(mf * 16 + q * 4 + r) * HD + nf * 16] = acc[mf][nf][r];
  }

  // ---- s/t epilogue: per-row dot with a_src/a_dst + 16-lane tree reduce ----
  {
    float a_s[4], a_d[4];
    #pragma unroll
    for (int nf = 0; nf < 4; ++nf) {
      a_s[nf] = att[head * 128 + nf * 16 + ml];
      a_d[nf] = att[head * 128 + 64 + nf * 16 + ml];
    }
    #pragma unroll
    for (int mf = 0; mf < 2; ++mf) {
      #pragma unroll
      for (int r = 0; r < 4; ++r) {
        float sp = 0.f, tp = 0.f;
        #pragma unroll
        for (int nf = 0; nf < 4; ++nf) {
          float c = acc[mf][nf][r];
          sp += c * a_s[nf]; tp += c * a_d[nf];
        }
        #pragma unroll
        for (int m = 1; m < 16; m <<= 1) {
          sp += __shfl_xor(sp, m, 64);
          tp += __shfl_xor(tp, m, 64);
        }
        if (ml == 0) {
          int row = nbase + w * 32 + mf * 16 + q * 4 + r;
          size_t o = ((size_t)b * NH + head) * NA + row;
          sG[o] = sp; tG[o] = tp;
        }
      }
    }
  }
}

// K2 (dim-split, in-place): block (bh, h2) owns columns [32*h2, 32*h2+32) of
// its bh slice — a DISJOINT byte range, so in-place io stays race-free with
// 2 blocks per bh (grid 512 -> 2 blocks/CU: two independent barrier domains
// per CU overlap each other's phase latencies; R4's 1-block/CU serialization
// was the 42us floor). Scalar work (sort/tables) duplicated per pair; all
// per-dim arithmetic is order-identical to R4 (bitwise-same output).
// Dots phase removed: s,t come precomputed from k1's epilogue.
__global__ __launch_bounds__(512, 2) void k2_fused(
    const float* __restrict__ sG, const float* __restrict__ tG,
    float* __restrict__ io) {
  __shared__ float tv[NA]; __shared__ int tpm[NA];
  __shared__ float sv[NA]; __shared__ int spm[NA];
  __shared__ float wp[NA]; __shared__ float wn[NA];
  __shared__ float rawP8[NW * 32]; __shared__ float rawN8[NW * 32];
  __shared__ float sufPc[(NW + 1) * 32]; __shared__ float preNc[(NW + 1) * 32];
  __shared__ float zps[NA + 1]; __shared__ float znp[NA + 1];
  __shared__ float szP[NC]; __shared__ float szN[NC];
  __shared__ float sufZ[NC + 1]; __shared__ float preZ[NC + 1];
  __shared__ float4 abi[NA];   // {A, B, 1/den, orig_row} per s-rank
  __shared__ int jsr[NA];      // js per s-rank (non-increasing)
  __shared__ int Earr[NA];     // E[j] = first rank with js <= j

  int blk = blockIdx.x;
  int bh = blk >> 1;
  int dbase = (blk & 1) * 32;         // this block's column slice
  int t = threadIdx.x;
  int lane = t & 63, w = t >> 6;
  float* vbase = io + (size_t)bh * NA * HD;

  // ---- load s,t (precomputed by k1 epilogue) ----
  float vt = tG[(size_t)bh * NA + t]; int it = t;
  float vs = sG[(size_t)bh * NA + t]; int is_ = t;

  // ---- dual hybrid bitonic sort (t asc, s asc), value+index in regs ----
  for (int size = 2; size <= NA; size <<= 1) {
    bool dirAsc = ((t & size) == 0);
    for (int stride = size >> 1; stride > 0; stride >>= 1) {
      float pt, ps; int pit, pis;
      if (stride >= 64) {
        tv[t] = vt; tpm[t] = it; sv[t] = vs; spm[t] = is_;
        __syncthreads();
        pt = tv[t ^ stride]; pit = tpm[t ^ stride];
        ps = sv[t ^ stride]; pis = spm[t ^ stride];
        __syncthreads();
      } else {
        pt = __shfl_xor(vt, stride, 64); pit = __shfl_xor(it, stride, 64);
        ps = __shfl_xor(vs, stride, 64); pis = __shfl_xor(is_, stride, 64);
      }
      bool mn = (((t & stride) == 0) == dirAsc);
      if (mn ? (pt < vt) : (pt > vt)) { vt = pt; it = pit; }
      if (mn ? (ps < vs) : (ps > vs)) { vs = ps; is_ = pis; }
    }
  }
  tv[t] = vt; tpm[t] = it; sv[t] = vs; spm[t] = is_;
  __syncthreads();

  float cmax = fmaxf(tv[NA - 1], 0.f);
  float amax = fmaxf(sv[NA - 1], 0.f);
  wp[t] = __expf(vt - cmax);
  wn[t] = __expf(NEG * vt - cmax);
  __syncthreads();

  // ---- phase A: wave w gathers 64 sorted rows x 32 dims, seeds (lane<32) ----
  float vreg[64];
  if (lane < 32) {
    float aP = 0.f, aN = 0.f;
    #pragma unroll 4
    for (int jj = 0; jj < 64; ++jj) {
      int j = (w << 6) + jj;
      float vv = vbase[(size_t)tpm[j] * HD + dbase + lane];
      vreg[jj] = vv;
      aP += wp[j] * vv;
      aN += wn[j] * vv;
    }
    rawP8[w * 32 + lane] = aP;
    rawN8[w * 32 + lane] = aN;
  }
  __syncthreads();

  // ---- cross-wave scans (32-wide) + scalar chunk sums (G=16) ----
  if (t < 32) {
    int d = t; float run = 0.f;
    sufPc[NW * 32 + d] = 0.f;
    for (int ww = NW - 1; ww >= 0; --ww) {
      run += rawP8[ww * 32 + d]; sufPc[ww * 32 + d] = run;
    }
  } else if (t < 64) {
    int d = t - 32; float run = 0.f;
    for (int ww = 0; ww <= NW; ++ww) {
      preNc[ww * 32 + d] = run;
      if (ww < NW) run += rawN8[ww * 32 + d];
    }
  } else if (t < 96) {
    int c = t - 64; float a = 0.f;
    for (int j = c * CH; j < c * CH + CH; ++j) a += wp[j];
    szP[c] = a;
  } else if (t < 128) {
    int c = t - 96; float a = 0.f;
    for (int j = c * CH; j < c * CH + CH; ++j) a += wn[j];
    szN[c] = a;
  }
  __syncthreads();

  if (t == 0) {
    float run = 0.f; sufZ[NC] = 0.f;
    for (int cc = NC - 1; cc >= 0; --cc) { run += szP[cc]; sufZ[cc] = run; }
  } else if (t == 1) {
    float run = 0.f;
    for (int cc = 0; cc <= NC; ++cc) { preZ[cc] = run; if (cc < NC) run += szN[cc]; }
  }
  __syncthreads();

  // ---- full-resolution scalar denominator tables ----
  {
    int ch = t >> 4;
    float a = 0.f;
    for (int k = t; k < ch * CH + CH; ++k) a += wp[k];
    zps[t] = a + sufZ[ch + 1];
    float b2 = 0.f;
    for (int k = ch * CH; k < t; ++k) b2 += wn[k];
    znp[t] = preZ[ch] + b2;
    if (t == 0) { zps[NA] = 0.f; znp[NA] = preZ[NC]; }
  }
  __syncthreads();

  // ---- per-rank info: thread t = s-rank t (holds vs, is_ in regs) ----
  {
    float A = __expf(vs - amax);
    float B = __expf(NEG * vs - amax);
    float key = -vs;
    int lo = 0, hi = NA;
    while (lo < hi) { int mid = (lo + hi) >> 1; if (tv[mid] < key) lo = mid + 1; else hi = mid; }
    float den = A * zps[lo] + B * znp[lo];
    float4 qv; qv.x = A; qv.y = B; qv.z = 1.f / den; qv.w = __int_as_float(is_);
    abi[t] = qv;
    jsr[t] = lo;
  }
  __syncthreads();

  // ---- E[j]: first rank with jsr <= j (jsr sorted descending) ----
  {
    int lo = 0, hi = NA;
    while (lo < hi) { int mid = (lo + hi) >> 1; if (jsr[mid] > t) lo = mid + 1; else hi = mid; }
    Earr[t] = lo;
  }
  __syncthreads();

  // ---- ascending sweep with inline emission (this block's 32 cols) ----
  if (lane < 32) {
    float sufPv = sufPc[w * 32 + lane];      // suffix incl. this wave's rows
    float preSeedN = preNc[w * 32 + lane];   // exact prefix before this wave
    float runN = 0.f;
    size_t obase = (size_t)bh * NA * HD + dbase + lane;
    int jb = w << 6;
    int eprev = (w == 0) ? NA : Earr[jb - 1];   // E[j-1] carried
    #pragma unroll 1
    for (int jj = 0; jj < 64; ++jj) {
      int j = jb + jj;
      int ecur = Earr[j];
      float preNv = preSeedN + runN;
      for (int r = ecur; r < eprev; ++r) {   // ranks with js == j
        float4 qv = abi[r];
        float x = (qv.x * sufPv + qv.y * preNv) * qv.z;
        int orow = __float_as_int(qv.w);
        io[obase + (size_t)orow * HD] = x > 0.f ? x : __expf(x) - 1.f;
      }
      float vv = vreg[jj];
      sufPv -= wp[j] * vv;
      runN  += wn[j] * vv;
      eprev = ecur;
    }
    if (w == NW - 1) {                       // group js == 512: [0, E[511])
      float preNv = preSeedN + runN;         // == total N prefix
      for (int r = 0; r < eprev; ++r) {
        float4 qv = abi[r];
        float x = (qv.y * preNv) * qv.z;     // sufP[512] == 0
        int orow = __float_as_int(qv.w);
        io[obase + (size_t)orow * HD] = x > 0.f ? x : __expf(x) - 1.f;
      }
    }
  }
}

extern "C" void kernel_launch(void* const* d_in, const int* in_sizes, int n_in,
                              void* d_out, int out_size, void* d_ws, size_t ws_size,
                              hipStream_t stream) {
  const float* h   = (const float*)d_in[0];
  const float* W   = (const float*)d_in[1];
  const float* att = (const float*)d_in[2];
  float* io = (float*)d_out;
  const size_t R = (size_t)BS * NH * NA;
  float* sG = (float*)d_ws;       // 512 KB
  float* tG = sG + R;             // 512 KB

  k1_mfma <<<dim3(1024),        dim3(256), 0, stream>>>(h, W, att, io, sG, tG);
  k2_fused<<<dim3(BS * NH * 2), dim3(512), 0, stream>>>(sG, tG, io);
}

// Round 11
// 146.008 us; speedup vs baseline: 1.0271x; 1.0271x over previous
//
#include <hip/hip_runtime.h>

#define BS 32
#define NA 512
#define ID 128
#define NH 8
#define HD 64
#define NHD 512   // NH*HD
#define NEG 0.2f
#define BPAD 136  // k1 B LDS col stride (bf16): 272B -> 2-way bank alias (free)
#define VSTR 520  // k2 V-transpose LDS row stride (bf16): 1040B, 16B-aligned

typedef short bf16x8 __attribute__((ext_vector_type(8)));
typedef float f32x4 __attribute__((ext_vector_type(4)));
typedef int   i32x4 __attribute__((ext_vector_type(4)));

__device__ inline unsigned f2bf_bits(float x) {   // RNE f32 -> bf16 bits
  unsigned u = __float_as_uint(x);
  return (u + 0x7FFFu + ((u >> 16) & 1u)) >> 16;
}

__device__ inline void split8(const float4& x, const float4& y,
                              bf16x8& hi, bf16x8& lo) {
  float f[8] = {x.x, x.y, x.z, x.w, y.x, y.y, y.z, y.w};
  #pragma unroll
  for (int j = 0; j < 8; ++j) {
    unsigned hb = f2bf_bits(f[j]);
    float r = f[j] - __uint_as_float(hb << 16);
    unsigned lb = f2bf_bits(r);
    hi[j] = (short)hb;
    lo[j] = (short)lb;
  }
}

__device__ inline unsigned selpair(float x0, float x1) {
  return (x0 >= 0.f ? 0xFFFFu : 0u) | (x1 >= 0.f ? 0xFFFF0000u : 0u);
}

// K1 (MFMA): hp = h @ W via split-bf16 3-pass, fp32 accumulate, + s/t
// epilogue from resident accumulators (verbatim R7 kernel — harness-verified).
// hp, s, t all to d_ws (free: harness poisons ws every iter regardless, R3).
__global__ __launch_bounds__(256, 4) void k1_mfma(
    const float* __restrict__ h, const float* __restrict__ W,
    const float* __restrict__ att, float* __restrict__ hp,
    float* __restrict__ sG, float* __restrict__ tG) {
  __shared__ unsigned short Bhi[64 * BPAD];
  __shared__ unsigned short Blo[64 * BPAD];

  int blk = blockIdx.x;
  int mt = blk >> 3;
  int n0 = (blk & 7) * 64;
  int m0 = mt * 128;
  int b = mt >> 2;
  int nbase = (mt & 3) * 128;
  int head = n0 >> 6;
  int t = threadIdx.x;
  int lane = t & 63, w = t >> 6;
  int q = lane >> 4, ml = lane & 15;

  {
    int c = t & 63, kq = t >> 6;
    const float* wsrc = W + (size_t)kq * 32 * NHD + n0 + c;
    #pragma unroll 4
    for (int kk = 0; kk < 32; ++kk) {
      int k = kq * 32 + kk;
      float x = wsrc[(size_t)kk * NHD];
      unsigned hb = f2bf_bits(x);
      float r = x - __uint_as_float(hb << 16);
      Bhi[c * BPAD + k] = (unsigned short)hb;
      Blo[c * BPAD + k] = (unsigned short)f2bf_bits(r);
    }
  }
  __syncthreads();

  f32x4 acc[2][4];
  #pragma unroll
  for (int mf = 0; mf < 2; ++mf)
    #pragma unroll
    for (int nf = 0; nf < 4; ++nf)
      acc[mf][nf] = (f32x4){0.f, 0.f, 0.f, 0.f};

  const float* A0 = h + (size_t)(m0 + w * 32 + ml) * ID;

  #pragma unroll
  for (int ks = 0; ks < 4; ++ks) {
    int ko = ks * 32 + q * 8;
    bf16x8 ah[2], al[2];
    #pragma unroll
    for (int mf = 0; mf < 2; ++mf) {
      const float* ap = A0 + mf * 16 * ID + ko;
      float4 f0 = *(const float4*)ap;
      float4 f1 = *(const float4*)(ap + 4);
      split8(f0, f1, ah[mf], al[mf]);
    }
    #pragma unroll
    for (int nf = 0; nf < 4; ++nf) {
      int bo = (nf * 16 + ml) * BPAD + ko;
      bf16x8 bh = *(const bf16x8*)&Bhi[bo];
      bf16x8 bl = *(const bf16x8*)&Blo[bo];
      #pragma unroll
      for (int mf = 0; mf < 2; ++mf) {
        acc[mf][nf] = __builtin_amdgcn_mfma_f32_16x16x32_bf16(ah[mf], bh, acc[mf][nf], 0, 0, 0);
        acc[mf][nf] = __builtin_amdgcn_mfma_f32_16x16x32_bf16(ah[mf], bl, acc[mf][nf], 0, 0, 0);
        acc[mf][nf] = __builtin_amdgcn_mfma_f32_16x16x32_bf16(al[mf], bh, acc[mf][nf], 0, 0, 0);
      }
    }
  }

  {
    float* ob = hp + (((size_t)b * NH + head) * NA + nbase + w * 32) * HD + ml;
    #pragma unroll
    for (int mf = 0; mf < 2; ++mf)
      #pragma unroll
      for (int nf = 0; nf < 4; ++nf)
        #pragma unroll
        for (int r = 0; r < 4; ++r)
          ob[(size_t)(mf * 16 + q * 4 + r) * HD + nf * 16] = acc[mf][nf][r];
  }

  {
    float a_s[4], a_d[4];
    #pragma unroll
    for (int nf = 0; nf < 4; ++nf) {
      a_s[nf] = att[head * 128 + nf * 16 + ml];
      a_d[nf] = att[head * 128 + 64 + nf * 16 + ml];
    }
    #pragma unroll
    for (int mf = 0; mf < 2; ++mf) {
      #pragma unroll
      for (int r = 0; r < 4; ++r) {
        float sp = 0.f, tp = 0.f;
        #pragma unroll
        for (int nf = 0; nf < 4; ++nf) {
          float c = acc[mf][nf][r];
          sp += c * a_s[nf]; tp += c * a_d[nf];
        }
        #pragma unroll
        for (int m = 1; m < 16; m <<= 1) {
          sp += __shfl_xor(sp, m, 64);
          tp += __shfl_xor(tp, m, 64);
        }
        if (ml == 0) {
          int row = nbase + w * 32 + mf * 16 + q * 4 + r;
          size_t o = ((size_t)b * NH + head) * NA + row;
          sG[o] = sp; tG[o] = tp;
        }
      }
    }
  }
}

// K2 (flash-MFMA): per bh, 512 threads = 8 waves x 64 output rows.
// e = lrelu(s_i + t_j) is rank-1 and lrelu monotone -> row max m_i =
// lrelu(s_i + tmax) known upfront (no online softmax). P factors as
// mask*(A_i*wp_j) + (1-mask)*(B_i*wn_j), wp/wn/A/B all <= 1. P1/P2 tiles are
// built from precomputed per-j bf16 hi/lo splits selected by a packed sign
// mask (no per-element exp), fed to mfma_16x16x32_bf16 with split-bf16
// 3-pass (err ~2^-16). den via ones-column B fragment (MFMA). Fragment
// conventions identical to k1 (same kappa-mapping both sides; HW-verified
// C/D layout). 3 barriers total; no sort, no scans.
__global__ __launch_bounds__(512) void k2_flash(
    const float* __restrict__ hp, const float* __restrict__ sG,
    const float* __restrict__ tG, float* __restrict__ out) {
  __shared__ unsigned short VTh[64 * VSTR];   // V^T hi (bf16), 65 KB
  __shared__ unsigned short VTl[64 * VSTR];   // V^T lo
  __shared__ uint4 wpk[256];                  // per j-pair {wph2,wpl2,wnh2,wnl2}
  __shared__ float tS[NA]; __shared__ float sS[NA];
  __shared__ float sA[NA]; __shared__ float sB[NA];
  __shared__ float red[8];

  int bh = blockIdx.x;
  int t = threadIdx.x;
  int lane = t & 63, w = t >> 6;
  int q = lane >> 4, ml = lane & 15;
  const float* vb = hp + (size_t)bh * NA * HD;

  // ---- prologue: tmax, A/B, wp/wn splits, V transpose into LDS ----
  float tj = tG[(size_t)bh * NA + t];
  float sj = sG[(size_t)bh * NA + t];
  tS[t] = tj; sS[t] = sj;
  {
    float m = tj;
    #pragma unroll
    for (int d = 32; d; d >>= 1) m = fmaxf(m, __shfl_xor(m, d, 64));
    if (lane == 0) red[w] = m;
  }
  __syncthreads();
  float tmax = fmaxf(fmaxf(fmaxf(red[0], red[1]), fmaxf(red[2], red[3])),
                     fmaxf(fmaxf(red[4], red[5]), fmaxf(red[6], red[7])));
  {
    float y = sj + tmax;
    float lr = fmaxf(y, 0.2f * y);          // lrelu(y) = max(y, 0.2y)
    sA[t] = __expf(y - lr);                 // <= 1
    sB[t] = __expf(0.2f * y - lr);          // <= 1
  }
  if (t < 256) {
    float t0 = tS[2 * t], t1 = tS[2 * t + 1];
    float wp0 = __expf(t0 - tmax), wp1 = __expf(t1 - tmax);
    float wn0 = __expf(0.2f * (t0 - tmax)), wn1 = __expf(0.2f * (t1 - tmax));
    unsigned h0 = f2bf_bits(wp0), h1 = f2bf_bits(wp1);
    unsigned l0 = f2bf_bits(wp0 - __uint_as_float(h0 << 16));
    unsigned l1 = f2bf_bits(wp1 - __uint_as_float(h1 << 16));
    unsigned n0 = f2bf_bits(wn0), n1 = f2bf_bits(wn1);
    unsigned m0 = f2bf_bits(wn0 - __uint_as_float(n0 << 16));
    unsigned m1 = f2bf_bits(wn1 - __uint_as_float(n1 << 16));
    uint4 pk;
    pk.x = h0 | (h1 << 16); pk.y = l0 | (l1 << 16);
    pk.z = n0 | (n1 << 16); pk.w = m0 | (m1 << 16);
    wpk[t] = pk;
  }
  {
    int d = t & 63, jb = (t >> 6) * 2;
    #pragma unroll 4
    for (int k = 0; k < 32; ++k) {
      int j0 = jb + k * 16;
      float v0 = vb[(size_t)j0 * HD + d];
      float v1 = vb[(size_t)(j0 + 1) * HD + d];
      unsigned h0 = f2bf_bits(v0), h1 = f2bf_bits(v1);
      unsigned l0 = f2bf_bits(v0 - __uint_as_float(h0 << 16));
      unsigned l1 = f2bf_bits(v1 - __uint_as_float(h1 << 16));
      *(unsigned*)&VTh[d * VSTR + j0] = h0 | (h1 << 16);
      *(unsigned*)&VTl[d * VSTR + j0] = l0 | (l1 << 16);
    }
  }
  __syncthreads();

  // ---- main loop: wave w owns rows [64w, 64w+64) ----
  int ri = w * 64;
  float sIr[4];
  #pragma unroll
  for (int mf = 0; mf < 4; ++mf) sIr[mf] = sS[ri + mf * 16 + ml];

  f32x4 acc1[4][4], acc2[4][4], aD1[4], aD2[4];
  #pragma unroll
  for (int mf = 0; mf < 4; ++mf) {
    #pragma unroll
    for (int nf = 0; nf < 4; ++nf) {
      acc1[mf][nf] = (f32x4){0.f, 0.f, 0.f, 0.f};
      acc2[mf][nf] = (f32x4){0.f, 0.f, 0.f, 0.f};
    }
    aD1[mf] = (f32x4){0.f, 0.f, 0.f, 0.f};
    aD2[mf] = (f32x4){0.f, 0.f, 0.f, 0.f};
  }

  bf16x8 ONESB;
  {
    int ov = (ml == 0) ? (int)0x3F803F80 : 0;   // bf16 1.0 pairs in col 0
    i32x4 o = {ov, ov, ov, ov};
    ONESB = __builtin_bit_cast(bf16x8, o);
  }

  #pragma unroll 1
  for (int ch = 0; ch < 16; ++ch) {
    int j0q = ch * 32 + q * 8;                 // my quarter's 8 k-slots
    float4 tqa = *(const float4*)&tS[j0q];
    float4 tqb = *(const float4*)&tS[j0q + 4];
    uint4 wk0 = wpk[(j0q >> 1) + 0];
    uint4 wk1 = wpk[(j0q >> 1) + 1];
    uint4 wk2 = wpk[(j0q >> 1) + 2];
    uint4 wk3 = wpk[(j0q >> 1) + 3];
    bf16x8 vh[4], vl[4];
    #pragma unroll
    for (int nf = 0; nf < 4; ++nf) {
      int dd = nf * 16 + ml;
      vh[nf] = *(const bf16x8*)&VTh[dd * VSTR + j0q];
      vl[nf] = *(const bf16x8*)&VTl[dd * VSTR + j0q];
    }
    #pragma unroll
    for (int mf = 0; mf < 4; ++mf) {
      float si = sIr[mf];
      unsigned s0 = selpair(si + tqa.x, si + tqa.y);
      unsigned s1 = selpair(si + tqa.z, si + tqa.w);
      unsigned s2 = selpair(si + tqb.x, si + tqb.y);
      unsigned s3 = selpair(si + tqb.z, si + tqb.w);
      i32x4 u1h = {(int)(wk0.x & s0), (int)(wk1.x & s1), (int)(wk2.x & s2), (int)(wk3.x & s3)};
      i32x4 u1l = {(int)(wk0.y & s0), (int)(wk1.y & s1), (int)(wk2.y & s2), (int)(wk3.y & s3)};
      i32x4 u2h = {(int)(wk0.z & ~s0), (int)(wk1.z & ~s1), (int)(wk2.z & ~s2), (int)(wk3.z & ~s3)};
      i32x4 u2l = {(int)(wk0.w & ~s0), (int)(wk1.w & ~s1), (int)(wk2.w & ~s2), (int)(wk3.w & ~s3)};
      bf16x8 p1h = __builtin_bit_cast(bf16x8, u1h);
      bf16x8 p1l = __builtin_bit_cast(bf16x8, u1l);
      bf16x8 p2h = __builtin_bit_cast(bf16x8, u2h);
      bf16x8 p2l = __builtin_bit_cast(bf16x8, u2l);
      #pragma unroll
      for (int nf = 0; nf < 4; ++nf) {
        acc1[mf][nf] = __builtin_amdgcn_mfma_f32_16x16x32_bf16(p1h, vh[nf], acc1[mf][nf], 0, 0, 0);
        acc1[mf][nf] = __builtin_amdgcn_mfma_f32_16x16x32_bf16(p1h, vl[nf], acc1[mf][nf], 0, 0, 0);
        acc1[mf][nf] = __builtin_amdgcn_mfma_f32_16x16x32_bf16(p1l, vh[nf], acc1[mf][nf], 0, 0, 0);
        acc2[mf][nf] = __builtin_amdgcn_mfma_f32_16x16x32_bf16(p2h, vh[nf], acc2[mf][nf], 0, 0, 0);
        acc2[mf][nf] = __builtin_amdgcn_mfma_f32_16x16x32_bf16(p2h, vl[nf], acc2[mf][nf], 0, 0, 0);
        acc2[mf][nf] = __builtin_amdgcn_mfma_f32_16x16x32_bf16(p2l, vh[nf], acc2[mf][nf], 0, 0, 0);
      }
      aD1[mf] = __builtin_amdgcn_mfma_f32_16x16x32_bf16(p1h, ONESB, aD1[mf], 0, 0, 0);
      aD1[mf] = __builtin_amdgcn_mfma_f32_16x16x32_bf16(p1l, ONESB, aD1[mf], 0, 0, 0);
      aD2[mf] = __builtin_amdgcn_mfma_f32_16x16x32_bf16(p2h, ONESB, aD2[mf], 0, 0, 0);
      aD2[mf] = __builtin_amdgcn_mfma_f32_16x16x32_bf16(p2l, ONESB, aD2[mf], 0, 0, 0);
    }
  }

  // ---- epilogue: combine, ELU, store (C layout: col=ml, row=4q+r) ----
  {
    float* ob = out + (size_t)bh * NA * HD;
    #pragma unroll
    for (int mf = 0; mf < 4; ++mf) {
      #pragma unroll
      for (int r = 0; r < 4; ++r) {
        float d1 = __shfl(aD1[mf][r], lane & 48, 64);   // den lives in col 0
        float d2 = __shfl(aD2[mf][r], lane & 48, 64);
        int row = ri + mf * 16 + q * 4 + r;
        float A = sA[row], B = sB[row];
        float inv = 1.f / (A * d1 + B * d2);
        #pragma unroll
        for (int nf = 0; nf < 4; ++nf) {
          float x = (A * acc1[mf][nf][r] + B * acc2[mf][nf][r]) * inv;
          ob[(size_t)row * HD + nf * 16 + ml] = x > 0.f ? x : __expf(x) - 1.f;
        }
      }
    }
  }
}

extern "C" void kernel_launch(void* const* d_in, const int* in_sizes, int n_in,
                              void* d_out, int out_size, void* d_ws, size_t ws_size,
                              hipStream_t stream) {
  const float* h   = (const float*)d_in[0];
  const float* W   = (const float*)d_in[1];
  const float* att = (const float*)d_in[2];
  float* out = (float*)d_out;
  const size_t R = (size_t)BS * NH * NA;
  float* hp = (float*)d_ws;        // 33.5 MB
  float* sG = hp + R * HD;         // 512 KB
  float* tG = sG + R;              // 512 KB

  k1_mfma <<<dim3(1024),    dim3(256), 0, stream>>>(h, W, att, hp, sG, tG);
  k2_flash<<<dim3(BS * NH), dim3(512), 0, stream>>>(hp, sG, tG, out);
}

// Round 12
// 132.322 us; speedup vs baseline: 1.1334x; 1.1034x over previous
//
#include <hip/hip_runtime.h>

#define BS 32
#define NA 512
#define ID 128
#define NH 8
#define HD 64
#define NHD 512   // NH*HD
#define NEG 0.2f
#define BPAD 136  // k1 B LDS col stride (bf16): 272B -> 2-way bank alias (free)
#define VSTR 520  // k2 V^T LDS row stride (bf16): 1040B == 16 mod 128 ->
                  // b128 reads AND writes tile the 32 banks (conflict-free)

typedef short bf16x8 __attribute__((ext_vector_type(8)));
typedef float f32x4 __attribute__((ext_vector_type(4)));
typedef int   i32x4 __attribute__((ext_vector_type(4)));

__device__ inline unsigned f2bf_bits(float x) {   // RNE f32 -> bf16 bits
  unsigned u = __float_as_uint(x);
  return (u + 0x7FFFu + ((u >> 16) & 1u)) >> 16;
}

__device__ inline void split8(const float4& x, const float4& y,
                              bf16x8& hi, bf16x8& lo) {
  float f[8] = {x.x, x.y, x.z, x.w, y.x, y.y, y.z, y.w};
  #pragma unroll
  for (int j = 0; j < 8; ++j) {
    unsigned hb = f2bf_bits(f[j]);
    float r = f[j] - __uint_as_float(hb << 16);
    unsigned lb = f2bf_bits(r);
    hi[j] = (short)hb;
    lo[j] = (short)lb;
  }
}

// K1 (MFMA): hp = h @ W via split-bf16 3-pass, fp32 accumulate, + s/t
// epilogue from resident accumulators (verbatim R7/R11 — harness-verified).
__global__ __launch_bounds__(256, 4) void k1_mfma(
    const float* __restrict__ h, const float* __restrict__ W,
    const float* __restrict__ att, float* __restrict__ hp,
    float* __restrict__ sG, float* __restrict__ tG) {
  __shared__ unsigned short Bhi[64 * BPAD];
  __shared__ unsigned short Blo[64 * BPAD];

  int blk = blockIdx.x;
  int mt = blk >> 3;
  int n0 = (blk & 7) * 64;
  int m0 = mt * 128;
  int b = mt >> 2;
  int nbase = (mt & 3) * 128;
  int head = n0 >> 6;
  int t = threadIdx.x;
  int lane = t & 63, w = t >> 6;
  int q = lane >> 4, ml = lane & 15;

  {
    int c = t & 63, kq = t >> 6;
    const float* wsrc = W + (size_t)kq * 32 * NHD + n0 + c;
    #pragma unroll 4
    for (int kk = 0; kk < 32; ++kk) {
      int k = kq * 32 + kk;
      float x = wsrc[(size_t)kk * NHD];
      unsigned hb = f2bf_bits(x);
      float r = x - __uint_as_float(hb << 16);
      Bhi[c * BPAD + k] = (unsigned short)hb;
      Blo[c * BPAD + k] = (unsigned short)f2bf_bits(r);
    }
  }
  __syncthreads();

  f32x4 acc[2][4];
  #pragma unroll
  for (int mf = 0; mf < 2; ++mf)
    #pragma unroll
    for (int nf = 0; nf < 4; ++nf)
      acc[mf][nf] = (f32x4){0.f, 0.f, 0.f, 0.f};

  const float* A0 = h + (size_t)(m0 + w * 32 + ml) * ID;

  #pragma unroll
  for (int ks = 0; ks < 4; ++ks) {
    int ko = ks * 32 + q * 8;
    bf16x8 ah[2], al[2];
    #pragma unroll
    for (int mf = 0; mf < 2; ++mf) {
      const float* ap = A0 + mf * 16 * ID + ko;
      float4 f0 = *(const float4*)ap;
      float4 f1 = *(const float4*)(ap + 4);
      split8(f0, f1, ah[mf], al[mf]);
    }
    #pragma unroll
    for (int nf = 0; nf < 4; ++nf) {
      int bo = (nf * 16 + ml) * BPAD + ko;
      bf16x8 bh = *(const bf16x8*)&Bhi[bo];
      bf16x8 bl = *(const bf16x8*)&Blo[bo];
      #pragma unroll
      for (int mf = 0; mf < 2; ++mf) {
        acc[mf][nf] = __builtin_amdgcn_mfma_f32_16x16x32_bf16(ah[mf], bh, acc[mf][nf], 0, 0, 0);
        acc[mf][nf] = __builtin_amdgcn_mfma_f32_16x16x32_bf16(ah[mf], bl, acc[mf][nf], 0, 0, 0);
        acc[mf][nf] = __builtin_amdgcn_mfma_f32_16x16x32_bf16(al[mf], bh, acc[mf][nf], 0, 0, 0);
      }
    }
  }

  {
    float* ob = hp + (((size_t)b * NH + head) * NA + nbase + w * 32) * HD + ml;
    #pragma unroll
    for (int mf = 0; mf < 2; ++mf)
      #pragma unroll
      for (int nf = 0; nf < 4; ++nf)
        #pragma unroll
        for (int r = 0; r < 4; ++r)
          ob[(size_t)(mf * 16 + q * 4 + r) * HD + nf * 16] = acc[mf][nf][r];
  }

  {
    float a_s[4], a_d[4];
    #pragma unroll
    for (int nf = 0; nf < 4; ++nf) {
      a_s[nf] = att[head * 128 + nf * 16 + ml];
      a_d[nf] = att[head * 128 + 64 + nf * 16 + ml];
    }
    #pragma unroll
    for (int mf = 0; mf < 2; ++mf) {
      #pragma unroll
      for (int r = 0; r < 4; ++r) {
        float sp = 0.f, tp = 0.f;
        #pragma unroll
        for (int nf = 0; nf < 4; ++nf) {
          float c = acc[mf][nf][r];
          sp += c * a_s[nf]; tp += c * a_d[nf];
        }
        #pragma unroll
        for (int m = 1; m < 16; m <<= 1) {
          sp += __shfl_xor(sp, m, 64);
          tp += __shfl_xor(tp, m, 64);
        }
        if (ml == 0) {
          int row = nbase + w * 32 + mf * 16 + q * 4 + r;
          size_t o = ((size_t)b * NH + head) * NA + row;
          sG[o] = sp; tG[o] = tp;
        }
      }
    }
  }
}

// K2 (flash-MFMA v2, merged P'): alpha~ = B*wn + mask*(A*wp - B*wn), so
//   num_i = B_i*wnV + (P' @ V)_i,  den_i = B_i*wnSum + rowsum(P'),
//   P'_ij = mask_ij*(A_i*wp_j - B_i*wn_j) in [0,1].
// ONE masked GEMM (split-bf16 3-pass) instead of R11's two: 14 MFMA and 80
// acc-VGPRs per (ch,mf) vs 28/160 — R11 spilled at VGPR cap 128 (WRITE 48MB
// = 14MB scratch). launch_bounds(512,2) raises the cap to 256. V^T staged
// with b128 writes at 1040B stride (==16 mod 128): conflict-free both ways.
__global__ __launch_bounds__(512, 2) void k2_flash(
    const float* __restrict__ hp, const float* __restrict__ sG,
    const float* __restrict__ tG, float* __restrict__ out) {
  __shared__ unsigned short VTh[64 * VSTR];   // V^T hi bf16, 65 KB
  __shared__ unsigned short VTl[64 * VSTR];   // V^T lo
  __shared__ float tS[NA]; __shared__ float sS[NA];
  __shared__ float sA[NA]; __shared__ float sB[NA];
  __shared__ float wpS[NA]; __shared__ float wnS[NA];
  __shared__ float wnVp[8 * 64]; __shared__ float wnV[64];
  __shared__ float red[8]; __shared__ float red2[8];

  int bh = blockIdx.x;
  int t = threadIdx.x;
  int lane = t & 63, w = t >> 6;
  int q = lane >> 4, ml = lane & 15;
  const float* vb = hp + (size_t)bh * NA * HD;

  // ---- prologue 1: t,s + tmax ----
  float tj = tG[(size_t)bh * NA + t];
  float sj = sG[(size_t)bh * NA + t];
  tS[t] = tj; sS[t] = sj;
  {
    float m = tj;
    #pragma unroll
    for (int d = 32; d; d >>= 1) m = fmaxf(m, __shfl_xor(m, d, 64));
    if (lane == 0) red[w] = m;
  }
  __syncthreads();
  float tmax = fmaxf(fmaxf(fmaxf(red[0], red[1]), fmaxf(red[2], red[3])),
                     fmaxf(fmaxf(red[4], red[5]), fmaxf(red[6], red[7])));

  // ---- prologue 2: weights + A/B + wnSum partial ----
  float wpj = __expf(tj - tmax);
  float wnj = __expf(0.2f * (tj - tmax));
  wpS[t] = wpj; wnS[t] = wnj;
  {
    float y = sj + tmax;
    float lr = fmaxf(y, 0.2f * y);          // lrelu = row max m_i
    sA[t] = __expf(y - lr);                 // <= 1
    sB[t] = __expf(0.2f * y - lr);          // <= 1
  }
  {
    float ws = wnj;
    #pragma unroll
    for (int d = 32; d; d >>= 1) ws += __shfl_xor(ws, d, 64);
    if (lane == 0) red2[w] = ws;
  }
  __syncthreads();
  float wnSum = ((red2[0] + red2[1]) + (red2[2] + red2[3])) +
                ((red2[4] + red2[5]) + (red2[6] + red2[7]));

  // ---- prologue 3: V transpose->LDS (b128 writes) + wnV partials ----
  {
    int d = lane;
    float part = 0.f;
    #pragma unroll 1
    for (int g = 0; g < 8; ++g) {
      int j0 = w * 64 + g * 8;
      unsigned hw0, hw1, hw2, hw3, lw0, lw1, lw2, lw3;
#define TRPAIR(KP, HW, LW)                                                    \
      { float v0 = vb[(size_t)(j0 + 2*(KP)) * HD + d];                        \
        float v1 = vb[(size_t)(j0 + 2*(KP) + 1) * HD + d];                    \
        part += wnS[j0 + 2*(KP)] * v0 + wnS[j0 + 2*(KP) + 1] * v1;            \
        unsigned h0 = f2bf_bits(v0), h1 = f2bf_bits(v1);                      \
        unsigned l0 = f2bf_bits(v0 - __uint_as_float(h0 << 16));              \
        unsigned l1 = f2bf_bits(v1 - __uint_as_float(h1 << 16));              \
        HW = h0 | (h1 << 16); LW = l0 | (l1 << 16); }
      TRPAIR(0, hw0, lw0) TRPAIR(1, hw1, lw1)
      TRPAIR(2, hw2, lw2) TRPAIR(3, hw3, lw3)
#undef TRPAIR
      uint4 hv = {hw0, hw1, hw2, hw3};
      uint4 lv = {lw0, lw1, lw2, lw3};
      *(uint4*)&VTh[d * VSTR + j0] = hv;
      *(uint4*)&VTl[d * VSTR + j0] = lv;
    }
    wnVp[w * 64 + d] = part;
  }
  __syncthreads();
  if (t < 64) {
    float a = 0.f;
    #pragma unroll
    for (int ww = 0; ww < 8; ++ww) a += wnVp[ww * 64 + t];
    wnV[t] = a;
  }
  __syncthreads();

  // ---- main loop: wave w owns rows [64w, 64w+64) ----
  int ri = w * 64;
  float sIr[4], Ar[4], Br[4];
  #pragma unroll
  for (int mf = 0; mf < 4; ++mf) {
    int rr = ri + mf * 16 + ml;          // A-fragment row = ml
    sIr[mf] = sS[rr]; Ar[mf] = sA[rr]; Br[mf] = sB[rr];
  }

  f32x4 acc[4][4], aD[4];
  #pragma unroll
  for (int mf = 0; mf < 4; ++mf) {
    #pragma unroll
    for (int nf = 0; nf < 4; ++nf) acc[mf][nf] = (f32x4){0.f, 0.f, 0.f, 0.f};
    aD[mf] = (f32x4){0.f, 0.f, 0.f, 0.f};
  }

  bf16x8 ONESB;
  {
    int ov = (ml == 0) ? (int)0x3F803F80 : 0;   // bf16 1.0 in col 0
    i32x4 o = {ov, ov, ov, ov};
    ONESB = __builtin_bit_cast(bf16x8, o);
  }

  #pragma unroll 1
  for (int ch = 0; ch < 16; ++ch) {
    int j0q = ch * 32 + q * 8;                 // my quarter's 8 k-slots
    float4 wpa = *(const float4*)&wpS[j0q];
    float4 wpb = *(const float4*)&wpS[j0q + 4];
    float4 wna = *(const float4*)&wnS[j0q];
    float4 wnb = *(const float4*)&wnS[j0q + 4];
    float4 tqa = *(const float4*)&tS[j0q];
    float4 tqb = *(const float4*)&tS[j0q + 4];
    bf16x8 vh[4], vl[4];
    #pragma unroll
    for (int nf = 0; nf < 4; ++nf) {
      int dd = nf * 16 + ml;
      vh[nf] = *(const bf16x8*)&VTh[dd * VSTR + j0q];
      vl[nf] = *(const bf16x8*)&VTl[dd * VSTR + j0q];
    }
    #pragma unroll
    for (int mf = 0; mf < 4; ++mf) {
      float si = sIr[mf], A = Ar[mf], B = Br[mf];
      float c0 = (si + tqa.x >= 0.f) ? fmaf(A, wpa.x, -(B * wna.x)) : 0.f;
      float c1 = (si + tqa.y >= 0.f) ? fmaf(A, wpa.y, -(B * wna.y)) : 0.f;
      float c2 = (si + tqa.z >= 0.f) ? fmaf(A, wpa.z, -(B * wna.z)) : 0.f;
      float c3 = (si + tqa.w >= 0.f) ? fmaf(A, wpa.w, -(B * wna.w)) : 0.f;
      float c4 = (si + tqb.x >= 0.f) ? fmaf(A, wpb.x, -(B * wnb.x)) : 0.f;
      float c5 = (si + tqb.y >= 0.f) ? fmaf(A, wpb.y, -(B * wnb.y)) : 0.f;
      float c6 = (si + tqb.z >= 0.f) ? fmaf(A, wpb.z, -(B * wnb.z)) : 0.f;
      float c7 = (si + tqb.w >= 0.f) ? fmaf(A, wpb.w, -(B * wnb.w)) : 0.f;
      unsigned h0 = f2bf_bits(c0), h1 = f2bf_bits(c1), h2 = f2bf_bits(c2),
               h3 = f2bf_bits(c3), h4 = f2bf_bits(c4), h5 = f2bf_bits(c5),
               h6 = f2bf_bits(c6), h7 = f2bf_bits(c7);
      i32x4 uh = {(int)(h0 | (h1 << 16)), (int)(h2 | (h3 << 16)),
                  (int)(h4 | (h5 << 16)), (int)(h6 | (h7 << 16))};
      unsigned l0 = f2bf_bits(c0 - __uint_as_float(h0 << 16));
      unsigned l1 = f2bf_bits(c1 - __uint_as_float(h1 << 16));
      unsigned l2 = f2bf_bits(c2 - __uint_as_float(h2 << 16));
      unsigned l3 = f2bf_bits(c3 - __uint_as_float(h3 << 16));
      unsigned l4 = f2bf_bits(c4 - __uint_as_float(h4 << 16));
      unsigned l5 = f2bf_bits(c5 - __uint_as_float(h5 << 16));
      unsigned l6 = f2bf_bits(c6 - __uint_as_float(h6 << 16));
      unsigned l7 = f2bf_bits(c7 - __uint_as_float(h7 << 16));
      i32x4 ul = {(int)(l0 | (l1 << 16)), (int)(l2 | (l3 << 16)),
                  (int)(l4 | (l5 << 16)), (int)(l6 | (l7 << 16))};
      bf16x8 Ph = __builtin_bit_cast(bf16x8, uh);
      bf16x8 Pl = __builtin_bit_cast(bf16x8, ul);
      #pragma unroll
      for (int nf = 0; nf < 4; ++nf) {
        acc[mf][nf] = __builtin_amdgcn_mfma_f32_16x16x32_bf16(Ph, vh[nf], acc[mf][nf], 0, 0, 0);
        acc[mf][nf] = __builtin_amdgcn_mfma_f32_16x16x32_bf16(Pl, vh[nf], acc[mf][nf], 0, 0, 0);
        acc[mf][nf] = __builtin_amdgcn_mfma_f32_16x16x32_bf16(Ph, vl[nf], acc[mf][nf], 0, 0, 0);
      }
      aD[mf] = __builtin_amdgcn_mfma_f32_16x16x32_bf16(Ph, ONESB, aD[mf], 0, 0, 0);
      aD[mf] = __builtin_amdgcn_mfma_f32_16x16x32_bf16(Pl, ONESB, aD[mf], 0, 0, 0);
    }
  }

  // ---- epilogue: den/num assembly, ELU, store ----
  {
    float* ob = out + (size_t)bh * NA * HD;
    #pragma unroll
    for (int mf = 0; mf < 4; ++mf) {
      #pragma unroll
      for (int r = 0; r < 4; ++r) {
        float dv = __shfl(aD[mf][r], lane & 48, 64);   // rowsum lives in col 0
        int row = ri + mf * 16 + q * 4 + r;
        float Brow = sB[row];
        float inv = 1.f / fmaf(Brow, wnSum, dv);
        #pragma unroll
        for (int nf = 0; nf < 4; ++nf) {
          int d = nf * 16 + ml;
          float x = fmaf(Brow, wnV[d], acc[mf][nf][r]) * inv;
          ob[(size_t)row * HD + d] = x > 0.f ? x : __expf(x) - 1.f;
        }
      }
    }
  }
}

extern "C" void kernel_launch(void* const* d_in, const int* in_sizes, int n_in,
                              void* d_out, int out_size, void* d_ws, size_t ws_size,
                              hipStream_t stream) {
  const float* h   = (const float*)d_in[0];
  const float* W   = (const float*)d_in[1];
  const float* att = (const float*)d_in[2];
  float* out = (float*)d_out;
  const size_t R = (size_t)BS * NH * NA;
  float* hp = (float*)d_ws;        // 33.5 MB
  float* sG = hp + R * HD;         // 512 KB
  float* tG = sG + R;              // 512 KB

  k1_mfma <<<dim3(1024),    dim3(256), 0, stream>>>(h, W, att, hp, sG, tG);
  k2_flash<<<dim3(BS * NH), dim3(512), 0, stream>>>(hp, sG, tG, out);
}

// Round 13
// 126.879 us; speedup vs baseline: 1.1820x; 1.0429x over previous
//
#include <hip/hip_runtime.h>

#define BS 32
#define NA 512
#define ID 128
#define NH 8
#define HD 64
#define NHD 512   // NH*HD
#define NEG 0.2f
#define BPAD 136  // k1 B LDS col stride (bf16): 272B -> 2-way bank alias (free)
#define VSTR 520  // k2 V^T LDS row stride (bf16): 1040B == 16 mod 128

typedef short bf16x8 __attribute__((ext_vector_type(8)));
typedef float f32x4 __attribute__((ext_vector_type(4)));
typedef int   i32x4 __attribute__((ext_vector_type(4)));

__device__ inline unsigned f2bf_bits(float x) {   // RNE f32 -> bf16 bits
  unsigned u = __float_as_uint(x);
  return (u + 0x7FFFu + ((u >> 16) & 1u)) >> 16;
}

__device__ inline void split8(const float4& x, const float4& y,
                              bf16x8& hi, bf16x8& lo) {
  float f[8] = {x.x, x.y, x.z, x.w, y.x, y.y, y.z, y.w};
  #pragma unroll
  for (int j = 0; j < 8; ++j) {
    unsigned hb = f2bf_bits(f[j]);
    float r = f[j] - __uint_as_float(hb << 16);
    unsigned lb = f2bf_bits(r);
    hi[j] = (short)hb;
    lo[j] = (short)lb;
  }
}

// K1 (MFMA): hp = h @ W via split-bf16 3-pass, fp32 accumulate, + s/t
// epilogue from resident accumulators (verbatim R7/R12 — harness-verified).
__global__ __launch_bounds__(256, 4) void k1_mfma(
    const float* __restrict__ h, const float* __restrict__ W,
    const float* __restrict__ att, float* __restrict__ hp,
    float* __restrict__ sG, float* __restrict__ tG) {
  __shared__ unsigned short Bhi[64 * BPAD];
  __shared__ unsigned short Blo[64 * BPAD];

  int blk = blockIdx.x;
  int mt = blk >> 3;
  int n0 = (blk & 7) * 64;
  int m0 = mt * 128;
  int b = mt >> 2;
  int nbase = (mt & 3) * 128;
  int head = n0 >> 6;
  int t = threadIdx.x;
  int lane = t & 63, w = t >> 6;
  int q = lane >> 4, ml = lane & 15;

  {
    int c = t & 63, kq = t >> 6;
    const float* wsrc = W + (size_t)kq * 32 * NHD + n0 + c;
    #pragma unroll 4
    for (int kk = 0; kk < 32; ++kk) {
      int k = kq * 32 + kk;
      float x = wsrc[(size_t)kk * NHD];
      unsigned hb = f2bf_bits(x);
      float r = x - __uint_as_float(hb << 16);
      Bhi[c * BPAD + k] = (unsigned short)hb;
      Blo[c * BPAD + k] = (unsigned short)f2bf_bits(r);
    }
  }
  __syncthreads();

  f32x4 acc[2][4];
  #pragma unroll
  for (int mf = 0; mf < 2; ++mf)
    #pragma unroll
    for (int nf = 0; nf < 4; ++nf)
      acc[mf][nf] = (f32x4){0.f, 0.f, 0.f, 0.f};

  const float* A0 = h + (size_t)(m0 + w * 32 + ml) * ID;

  #pragma unroll
  for (int ks = 0; ks < 4; ++ks) {
    int ko = ks * 32 + q * 8;
    bf16x8 ah[2], al[2];
    #pragma unroll
    for (int mf = 0; mf < 2; ++mf) {
      const float* ap = A0 + mf * 16 * ID + ko;
      float4 f0 = *(const float4*)ap;
      float4 f1 = *(const float4*)(ap + 4);
      split8(f0, f1, ah[mf], al[mf]);
    }
    #pragma unroll
    for (int nf = 0; nf < 4; ++nf) {
      int bo = (nf * 16 + ml) * BPAD + ko;
      bf16x8 bh = *(const bf16x8*)&Bhi[bo];
      bf16x8 bl = *(const bf16x8*)&Blo[bo];
      #pragma unroll
      for (int mf = 0; mf < 2; ++mf) {
        acc[mf][nf] = __builtin_amdgcn_mfma_f32_16x16x32_bf16(ah[mf], bh, acc[mf][nf], 0, 0, 0);
        acc[mf][nf] = __builtin_amdgcn_mfma_f32_16x16x32_bf16(ah[mf], bl, acc[mf][nf], 0, 0, 0);
        acc[mf][nf] = __builtin_amdgcn_mfma_f32_16x16x32_bf16(al[mf], bh, acc[mf][nf], 0, 0, 0);
      }
    }
  }

  {
    float* ob = hp + (((size_t)b * NH + head) * NA + nbase + w * 32) * HD + ml;
    #pragma unroll
    for (int mf = 0; mf < 2; ++mf)
      #pragma unroll
      for (int nf = 0; nf < 4; ++nf)
        #pragma unroll
        for (int r = 0; r < 4; ++r)
          ob[(size_t)(mf * 16 + q * 4 + r) * HD + nf * 16] = acc[mf][nf][r];
  }

  {
    float a_s[4], a_d[4];
    #pragma unroll
    for (int nf = 0; nf < 4; ++nf) {
      a_s[nf] = att[head * 128 + nf * 16 + ml];
      a_d[nf] = att[head * 128 + 64 + nf * 16 + ml];
    }
    #pragma unroll
    for (int mf = 0; mf < 2; ++mf) {
      #pragma unroll
      for (int r = 0; r < 4; ++r) {
        float sp = 0.f, tp = 0.f;
        #pragma unroll
        for (int nf = 0; nf < 4; ++nf) {
          float c = acc[mf][nf][r];
          sp += c * a_s[nf]; tp += c * a_d[nf];
        }
        #pragma unroll
        for (int m = 1; m < 16; m <<= 1) {
          sp += __shfl_xor(sp, m, 64);
          tp += __shfl_xor(tp, m, 64);
        }
        if (ml == 0) {
          int row = nbase + w * 32 + mf * 16 + q * 4 + r;
          size_t o = ((size_t)b * NH + head) * NA + row;
          sG[o] = sp; tG[o] = tp;
        }
      }
    }
  }
}

// Truncation hi/lo split helpers for P' build: hi = bit-truncated bf16 (valid
// bf16, subtraction c-hi exact), lo = truncated bf16 of remainder. Residual
// ~2^-16 relative — same class as RNE split, ~half the VALU.
__device__ inline unsigned packpair_hi(float c0, float c1, float& r0, float& r1) {
  unsigned u0 = __float_as_uint(c0), u1 = __float_as_uint(c1);
  r0 = c0 - __uint_as_float(u0 & 0xFFFF0000u);
  r1 = c1 - __uint_as_float(u1 & 0xFFFF0000u);
  return (u0 >> 16) | (u1 & 0xFFFF0000u);
}
__device__ inline unsigned packpair_tr(float r0, float r1) {
  return (__float_as_uint(r0) >> 16) | (__float_as_uint(r1) & 0xFFFF0000u);
}

// K2 (flash-MFMA v3): R12's merged-P' algebra, re-geometried for overlap:
// 1024 threads = 16 waves x 32 rows -> 4 waves/SIMD, so one wave's P'-build
// VALU hides under another's MFMA (R12 at 2 waves/SIMD stalled: VALU 52%,
// Mfma 22%, 51us). Truncation split replaces RNE (half the VALU, same 2^-16
// class). acc = 40 VGPR/thread; Ph/Pl built per-mf before nf loop, vh/vl
// loaded once per nf -> ~105 live regs < 128 cap.
__global__ __launch_bounds__(1024) void k2_flash(
    const float* __restrict__ hp, const float* __restrict__ sG,
    const float* __restrict__ tG, float* __restrict__ out) {
  __shared__ unsigned short VTh[64 * VSTR];   // V^T hi bf16, 65 KB
  __shared__ unsigned short VTl[64 * VSTR];   // V^T lo
  __shared__ float tS[NA]; __shared__ float sS[NA];
  __shared__ float sA[NA]; __shared__ float sB[NA];
  __shared__ float wpS[NA]; __shared__ float wnS[NA];
  __shared__ float wnVp[16 * 64]; __shared__ float wnV[64];
  __shared__ float red[8]; __shared__ float red2[8];

  int bh = blockIdx.x;
  int t = threadIdx.x;
  int lane = t & 63, w = t >> 6;          // w in [0,16)
  int q = lane >> 4, ml = lane & 15;
  const float* vb = hp + (size_t)bh * NA * HD;

  // ---- prologue 1: t,s + tmax (waves 0..7 hold the 512 values) ----
  float tj = 0.f, sj = 0.f;
  if (t < NA) {
    tj = tG[(size_t)bh * NA + t];
    sj = sG[(size_t)bh * NA + t];
    tS[t] = tj; sS[t] = sj;
  }
  if (w < 8) {
    float m = tj;
    #pragma unroll
    for (int d = 32; d; d >>= 1) m = fmaxf(m, __shfl_xor(m, d, 64));
    if (lane == 0) red[w] = m;
  }
  __syncthreads();
  float tmax = fmaxf(fmaxf(fmaxf(red[0], red[1]), fmaxf(red[2], red[3])),
                     fmaxf(fmaxf(red[4], red[5]), fmaxf(red[6], red[7])));

  // ---- prologue 2: weights + A/B + wnSum ----
  float wnj = 0.f;
  if (t < NA) {
    float wpj = __expf(tj - tmax);
    wnj = __expf(0.2f * (tj - tmax));
    wpS[t] = wpj; wnS[t] = wnj;
    float y = sj + tmax;
    float lr = fmaxf(y, 0.2f * y);          // lrelu = row max m_i
    sA[t] = __expf(y - lr);                 // <= 1
    sB[t] = __expf(0.2f * y - lr);          // <= 1
  }
  if (w < 8) {
    float ws = wnj;
    #pragma unroll
    for (int d = 32; d; d >>= 1) ws += __shfl_xor(ws, d, 64);
    if (lane == 0) red2[w] = ws;
  }
  __syncthreads();
  float wnSum = ((red2[0] + red2[1]) + (red2[2] + red2[3])) +
                ((red2[4] + red2[5]) + (red2[6] + red2[7]));

  // ---- prologue 3: V^T -> LDS (b128 writes) + wnV partials ----
  {
    int d = lane;
    float part = 0.f;
    #pragma unroll 1
    for (int g = 0; g < 4; ++g) {
      int j0 = w * 32 + g * 8;
      unsigned hw0, hw1, hw2, hw3, lw0, lw1, lw2, lw3;
#define TRPAIR(KP, HW, LW)                                                    \
      { float v0 = vb[(size_t)(j0 + 2*(KP)) * HD + d];                        \
        float v1 = vb[(size_t)(j0 + 2*(KP) + 1) * HD + d];                    \
        part += wnS[j0 + 2*(KP)] * v0 + wnS[j0 + 2*(KP) + 1] * v1;            \
        float r0_, r1_;                                                       \
        HW = packpair_hi(v0, v1, r0_, r1_);                                   \
        LW = packpair_tr(r0_, r1_); }
      TRPAIR(0, hw0, lw0) TRPAIR(1, hw1, lw1)
      TRPAIR(2, hw2, lw2) TRPAIR(3, hw3, lw3)
#undef TRPAIR
      uint4 hv = {hw0, hw1, hw2, hw3};
      uint4 lv = {lw0, lw1, lw2, lw3};
      *(uint4*)&VTh[d * VSTR + j0] = hv;
      *(uint4*)&VTl[d * VSTR + j0] = lv;
    }
    wnVp[w * 64 + d] = part;
  }
  __syncthreads();
  if (t < 64) {
    float a = 0.f;
    #pragma unroll
    for (int ww = 0; ww < 16; ++ww) a += wnVp[ww * 64 + t];
    wnV[t] = a;
  }
  __syncthreads();

  // ---- main loop: wave w owns rows [32w, 32w+32) ----
  int ri = w * 32;
  float sIr[2], Ar[2], Br[2];
  #pragma unroll
  for (int mf = 0; mf < 2; ++mf) {
    int rr = ri + mf * 16 + ml;          // A-fragment row = ml
    sIr[mf] = sS[rr]; Ar[mf] = sA[rr]; Br[mf] = sB[rr];
  }

  f32x4 acc[2][4], aD[2];
  #pragma unroll
  for (int mf = 0; mf < 2; ++mf) {
    #pragma unroll
    for (int nf = 0; nf < 4; ++nf) acc[mf][nf] = (f32x4){0.f, 0.f, 0.f, 0.f};
    aD[mf] = (f32x4){0.f, 0.f, 0.f, 0.f};
  }

  bf16x8 ONESB;
  {
    int ov = (ml == 0) ? (int)0x3F803F80 : 0;   // bf16 1.0 in col 0
    i32x4 o = {ov, ov, ov, ov};
    ONESB = __builtin_bit_cast(bf16x8, o);
  }

  #pragma unroll 1
  for (int ch = 0; ch < 16; ++ch) {
    int j0q = ch * 32 + q * 8;                 // my quarter's 8 k-slots
    float4 wpa = *(const float4*)&wpS[j0q];
    float4 wpb = *(const float4*)&wpS[j0q + 4];
    float4 wna = *(const float4*)&wnS[j0q];
    float4 wnb = *(const float4*)&wnS[j0q + 4];
    float4 tqa = *(const float4*)&tS[j0q];
    float4 tqb = *(const float4*)&tS[j0q + 4];
    bf16x8 Ph[2], Pl[2];
    #pragma unroll
    for (int mf = 0; mf < 2; ++mf) {
      float si = sIr[mf], A = Ar[mf], B = Br[mf];
      float c0 = (si + tqa.x >= 0.f) ? fmaf(A, wpa.x, -(B * wna.x)) : 0.f;
      float c1 = (si + tqa.y >= 0.f) ? fmaf(A, wpa.y, -(B * wna.y)) : 0.f;
      float c2 = (si + tqa.z >= 0.f) ? fmaf(A, wpa.z, -(B * wna.z)) : 0.f;
      float c3 = (si + tqa.w >= 0.f) ? fmaf(A, wpa.w, -(B * wna.w)) : 0.f;
      float c4 = (si + tqb.x >= 0.f) ? fmaf(A, wpb.x, -(B * wnb.x)) : 0.f;
      float c5 = (si + tqb.y >= 0.f) ? fmaf(A, wpb.y, -(B * wnb.y)) : 0.f;
      float c6 = (si + tqb.z >= 0.f) ? fmaf(A, wpb.z, -(B * wnb.z)) : 0.f;
      float c7 = (si + tqb.w >= 0.f) ? fmaf(A, wpb.w, -(B * wnb.w)) : 0.f;
      float r0, r1, r2, r3, r4, r5, r6, r7;
      i32x4 uh = {(int)packpair_hi(c0, c1, r0, r1),
                  (int)packpair_hi(c2, c3, r2, r3),
                  (int)packpair_hi(c4, c5, r4, r5),
                  (int)packpair_hi(c6, c7, r6, r7)};
      i32x4 ul = {(int)packpair_tr(r0, r1), (int)packpair_tr(r2, r3),
                  (int)packpair_tr(r4, r5), (int)packpair_tr(r6, r7)};
      Ph[mf] = __builtin_bit_cast(bf16x8, uh);
      Pl[mf] = __builtin_bit_cast(bf16x8, ul);
    }
    #pragma unroll
    for (int nf = 0; nf < 4; ++nf) {
      int dd = nf * 16 + ml;
      bf16x8 vh = *(const bf16x8*)&VTh[dd * VSTR + j0q];
      bf16x8 vl = *(const bf16x8*)&VTl[dd * VSTR + j0q];
      #pragma unroll
      for (int mf = 0; mf < 2; ++mf) {
        acc[mf][nf] = __builtin_amdgcn_mfma_f32_16x16x32_bf16(Ph[mf], vh, acc[mf][nf], 0, 0, 0);
        acc[mf][nf] = __builtin_amdgcn_mfma_f32_16x16x32_bf16(Pl[mf], vh, acc[mf][nf], 0, 0, 0);
        acc[mf][nf] = __builtin_amdgcn_mfma_f32_16x16x32_bf16(Ph[mf], vl, acc[mf][nf], 0, 0, 0);
      }
    }
    #pragma unroll
    for (int mf = 0; mf < 2; ++mf) {
      aD[mf] = __builtin_amdgcn_mfma_f32_16x16x32_bf16(Ph[mf], ONESB, aD[mf], 0, 0, 0);
      aD[mf] = __builtin_amdgcn_mfma_f32_16x16x32_bf16(Pl[mf], ONESB, aD[mf], 0, 0, 0);
    }
  }

  // ---- epilogue: den/num assembly, ELU, store ----
  {
    float* ob = out + (size_t)bh * NA * HD;
    #pragma unroll
    for (int mf = 0; mf < 2; ++mf) {
      #pragma unroll
      for (int r = 0; r < 4; ++r) {
        float dv = __shfl(aD[mf][r], lane & 48, 64);   // rowsum lives in col 0
        int row = ri + mf * 16 + q * 4 + r;
        float Brow = sB[row];
        float inv = 1.f / fmaf(Brow, wnSum, dv);
        #pragma unroll
        for (int nf = 0; nf < 4; ++nf) {
          int d = nf * 16 + ml;
          float x = fmaf(Brow, wnV[d], acc[mf][nf][r]) * inv;
          ob[(size_t)row * HD + d] = x > 0.f ? x : __expf(x) - 1.f;
        }
      }
    }
  }
}

extern "C" void kernel_launch(void* const* d_in, const int* in_sizes, int n_in,
                              void* d_out, int out_size, void* d_ws, size_t ws_size,
                              hipStream_t stream) {
  const float* h   = (const float*)d_in[0];
  const float* W   = (const float*)d_in[1];
  const float* att = (const float*)d_in[2];
  float* out = (float*)d_out;
  const size_t R = (size_t)BS * NH * NA;
  float* hp = (float*)d_ws;        // 33.5 MB
  float* sG = hp + R * HD;         // 512 KB
  float* tG = sG + R;              // 512 KB

  k1_mfma <<<dim3(1024),     dim3(256),  0, stream>>>(h, W, att, hp, sG, tG);
  k2_flash<<<dim3(BS * NH), dim3(1024), 0, stream>>>(hp, sG, tG, out);
}